// Round 7
// baseline (5336.633 us; speedup 1.0000x reference)
//
#include <hip/hip_runtime.h>
#include <cstddef>

// Problem constants (fixed by the reference)
static const int WW = 8192;     // width (atoms)
static const int DD = 768;      // input dim
static const int BBATCH = 8192; // batch
static const int KSEL = 32;     // MP steps

typedef double f64x4 __attribute__((ext_vector_type(4)));

// ---------------------------------------------------------------------------
// Runtime probe of the v_mfma_f64_16x16x4 D-fragment wiring (HW-verified in
// R2: hardcoded map failed, probe-derived map passes). Assumes only the INPUT
// gather (i=lane%16, k=lane/16 for A; j=lane%16, k=lane/16 for B). Decodes
// the (lane,reg)->(i,j) output map for ANY wiring; clamped so a broken
// assumption cannot write OOB. Called at epilogue only.
// ---------------------------------------------------------------------------
__device__ inline void mfma_f64_probe(int lane, int* pi, int* pj) {
    f64x4 z0{0.0, 0.0, 0.0, 0.0};
    f64x4 d1 = __builtin_amdgcn_mfma_f64_16x16x4f64((double)lane, 1.0, z0, 0, 0, 0);
    f64x4 d2 = __builtin_amdgcn_mfma_f64_16x16x4f64(1.0, (double)lane, z0, 0, 0, 0);
#pragma unroll
    for (int v = 0; v < 4; ++v) {
        pi[v] = (((int)d1[v] - 96) >> 2) & 15;
        pj[v] = (((int)d2[v] - 96) >> 2) & 15;
    }
}

// ---------------------------------------------------------------------------
// column norms of Ad [D, W] -> nrm[W] = max(||Ad[:,w]||, 1e-8), fp64 accumulate
// ---------------------------------------------------------------------------
__global__ __launch_bounds__(256) void colnorm_kernel(const float* __restrict__ Ad,
                                                      float* __restrict__ nrm) {
    int w = blockIdx.x * 256 + threadIdx.x;
    double s = 0.0;
    for (int d = 0; d < DD; ++d) {
        double v = (double)Ad[(size_t)d * WW + w];
        s += v * v;
    }
    nrm[w] = fmaxf((float)sqrt(s), 1e-8f);
}

// ---------------------------------------------------------------------------
// AdnT[w, d] = Ad[d, w] / nrm[w]   (LDS tiled transpose, 32x32)
// ---------------------------------------------------------------------------
__global__ __launch_bounds__(256) void transpose_scale_kernel(const float* __restrict__ Ad,
                                                              const float* __restrict__ nrm,
                                                              float* __restrict__ AdnT) {
    __shared__ float tile[32][33];
    int wb = blockIdx.x * 32;
    int db = blockIdx.y * 32;
    int tx = threadIdx.x;   // 0..31
    int ty = threadIdx.y;   // 0..7
    for (int i = ty; i < 32; i += 8)
        tile[i][tx] = Ad[(size_t)(db + i) * WW + (wb + tx)];
    __syncthreads();
    for (int i = ty; i < 32; i += 8)
        AdnT[(size_t)(wb + i) * DD + (db + tx)] = tile[tx][i] / nrm[wb + i];
}

// ---------------------------------------------------------------------------
// Gram via f64 MFMA (R3 config = measured best: ~1093-1123 us, MfmaUtil ~65%).
// 128x64 block, 4 waves 2x2, each wave 64x32 = 4x2 tiles, BK=16, 25 KiB LDS.
// Upper blocks only (bx >= 2*by); mirror fills strict-lower tiles.
// ---------------------------------------------------------------------------
__global__ __launch_bounds__(256, 2) void gram_mfma_f64_kernel(const float* __restrict__ Ad,
                                                               const float* __restrict__ nrm,
                                                               float* __restrict__ G) {
    const int bx = blockIdx.x, by = blockIdx.y;
    if (bx < 2 * by) return;   // block entirely strictly-lower -> skip (mirror fills)
    __shared__ __align__(16) double As[16 * 130];   // As[k][i], i=0..127
    __shared__ __align__(16) double Bs[16 * 66];    // Bs[k][j], j=0..63
    const int tid = threadIdx.x;
    const int lane = tid & 63;
    const int wv = tid >> 6;        // wave 0..3
    const int wr = wv >> 1;         // 0..1 row half (64 rows)
    const int wc = wv & 1;          // 0..1 col half (32 cols)
    const int i0 = by * 128;
    const int j0 = bx * 64;
    const int ar0 = tid >> 6;        // 0..3
    const int ap0 = (tid & 63) * 2;  // 0..126
    const int brow = tid >> 5;       // 0..7
    const int bpos = (tid & 31) * 2; // 0..62

    f64x4 acc[4][2];
#pragma unroll
    for (int m = 0; m < 4; ++m)
#pragma unroll
        for (int n = 0; n < 2; ++n)
            acc[m][n] = f64x4{0.0, 0.0, 0.0, 0.0};

    float2 aL[4], bl0, bl1;
#pragma unroll
    for (int q = 0; q < 4; ++q)
        aL[q] = *(const float2*)&Ad[(size_t)(4 * q + ar0) * WW + i0 + ap0];
    bl0 = *(const float2*)&Ad[(size_t)(brow) * WW + j0 + bpos];
    bl1 = *(const float2*)&Ad[(size_t)(8 + brow) * WW + j0 + bpos];

    for (int k0 = 0; k0 < DD; k0 += 16) {
        __syncthreads();   // previous iteration's LDS reads done
#pragma unroll
        for (int q = 0; q < 4; ++q) {
            double2 da; da.x = (double)aL[q].x; da.y = (double)aL[q].y;
            *(double2*)&As[(4 * q + ar0) * 130 + ap0] = da;
        }
        {
            double2 d0; d0.x = (double)bl0.x; d0.y = (double)bl0.y;
            double2 d1; d1.x = (double)bl1.x; d1.y = (double)bl1.y;
            *(double2*)&Bs[brow * 66 + bpos] = d0;
            *(double2*)&Bs[(8 + brow) * 66 + bpos] = d1;
        }
        __syncthreads();
        if (k0 + 16 < DD) {   // prefetch next panel; latency hides under MFMAs
#pragma unroll
            for (int q = 0; q < 4; ++q)
                aL[q] = *(const float2*)&Ad[(size_t)(k0 + 16 + 4 * q + ar0) * WW + i0 + ap0];
            bl0 = *(const float2*)&Ad[(size_t)(k0 + 16 + brow) * WW + j0 + bpos];
            bl1 = *(const float2*)&Ad[(size_t)(k0 + 24 + brow) * WW + j0 + bpos];
        }
#pragma unroll
        for (int kc = 0; kc < 4; ++kc) {
            const int krow = kc * 4 + (lane >> 4);
            const double* ap = &As[krow * 130 + wr * 64 + (lane & 15)];
            const double* bp = &Bs[krow * 66 + wc * 32 + (lane & 15)];
            double aF[4], bF[2];
#pragma unroll
            for (int m = 0; m < 4; ++m) aF[m] = ap[m * 16];
#pragma unroll
            for (int n = 0; n < 2; ++n) bF[n] = bp[n * 16];
#pragma unroll
            for (int m = 0; m < 4; ++m)
#pragma unroll
                for (int n = 0; n < 2; ++n)
                    acc[m][n] = __builtin_amdgcn_mfma_f64_16x16x4f64(aF[m], bF[n],
                                                                     acc[m][n], 0, 0, 0);
        }
    }

    int pi[4], pj[4];
    mfma_f64_probe(lane, pi, pj);
#pragma unroll
    for (int m = 0; m < 4; ++m) {
#pragma unroll
        for (int v = 0; v < 4; ++v) {
            int row = i0 + wr * 64 + m * 16 + pi[v];
            double inv_i = 1.0 / (double)nrm[row];
#pragma unroll
            for (int n = 0; n < 2; ++n) {
                int col = j0 + wc * 32 + n * 16 + pj[v];
                G[(size_t)row * WW + col] = (float)(acc[m][n][v] * inv_i / (double)nrm[col]);
            }
        }
    }
}

// ---------------------------------------------------------------------------
// mirror: G[j,i] = G[i,j] for strict-upper 64x64 tiles
// ---------------------------------------------------------------------------
__global__ __launch_bounds__(256) void mirror_kernel(float* __restrict__ G) {
    const int ti = blockIdx.y;
    const int tj = blockIdx.x;
    if (tj <= ti) return;
    __shared__ float tile[64][65];
    const int t = threadIdx.x;
    const int c4 = (t & 15) * 4;   // 0..60
    const int r  = t >> 4;         // 0..15
#pragma unroll
    for (int rr = r; rr < 64; rr += 16) {
        float4 v = *(const float4*)&G[(size_t)(ti * 64 + rr) * WW + tj * 64 + c4];
        tile[rr][c4 + 0] = v.x;
        tile[rr][c4 + 1] = v.y;
        tile[rr][c4 + 2] = v.z;
        tile[rr][c4 + 3] = v.w;
    }
    __syncthreads();
#pragma unroll
    for (int rr = r; rr < 64; rr += 16) {
        float4 v = make_float4(tile[c4 + 0][rr], tile[c4 + 1][rr],
                               tile[c4 + 2][rr], tile[c4 + 3][rr]);
        *(float4*)&G[(size_t)(tj * 64 + rr) * WW + ti * 64 + c4] = v;
    }
}

// ---------------------------------------------------------------------------
// z via f64 MFMA (R4 config): Z[b,w] = (sum_d (X[b,d]-bd[d]) * Ad[d,w]) / nrm[w]
// 64x128 block, 4 waves (1x4), each wave 4x2 tiles, BK=32.
// ---------------------------------------------------------------------------
__global__ __launch_bounds__(256, 2) void z_mfma_f64_kernel(const float* __restrict__ X,
                                                            const float* __restrict__ Ad,
                                                            const float* __restrict__ bd,
                                                            const float* __restrict__ nrm,
                                                            float* __restrict__ Z) {
    __shared__ __align__(16) double As[32 * 66];    // As[k][b], b=0..63
    __shared__ __align__(16) double Bs[32 * 130];   // Bs[k][w], w=0..127
    const int tid = threadIdx.x;
    const int lane = tid & 63;
    const int wcol = tid >> 6;      // wave 0..3 -> 32-col group
    const int b0 = blockIdx.y * 64;
    const int w0 = blockIdx.x * 128;
    const int r  = tid >> 2;        // 0..63 batch row (A staging)
    const int k8 = (tid & 3) * 8;   // k offset 0..24
    const int br0 = tid >> 6;
    const int bp0 = (tid & 63) * 2;

    f64x4 acc[4][2];
#pragma unroll
    for (int m = 0; m < 4; ++m)
#pragma unroll
        for (int n = 0; n < 2; ++n)
            acc[m][n] = f64x4{0.0, 0.0, 0.0, 0.0};

    float4 a0L, a1L; float2 bL[8];
    {
        float4 bias0 = *(const float4*)&bd[k8];
        float4 bias1 = *(const float4*)&bd[k8 + 4];
        float4 a0 = *(const float4*)&X[(size_t)(b0 + r) * DD + k8];
        float4 a1 = *(const float4*)&X[(size_t)(b0 + r) * DD + k8 + 4];
        a0.x -= bias0.x; a0.y -= bias0.y; a0.z -= bias0.z; a0.w -= bias0.w;
        a1.x -= bias1.x; a1.y -= bias1.y; a1.z -= bias1.z; a1.w -= bias1.w;
        a0L = a0; a1L = a1;
#pragma unroll
        for (int q = 0; q < 8; ++q)
            bL[q] = *(const float2*)&Ad[(size_t)(4 * q + br0) * WW + w0 + bp0];
    }

    for (int k0 = 0; k0 < DD; k0 += 32) {
        __syncthreads();   // previous iteration's LDS reads done
        As[(k8 + 0) * 66 + r] = (double)a0L.x;
        As[(k8 + 1) * 66 + r] = (double)a0L.y;
        As[(k8 + 2) * 66 + r] = (double)a0L.z;
        As[(k8 + 3) * 66 + r] = (double)a0L.w;
        As[(k8 + 4) * 66 + r] = (double)a1L.x;
        As[(k8 + 5) * 66 + r] = (double)a1L.y;
        As[(k8 + 6) * 66 + r] = (double)a1L.z;
        As[(k8 + 7) * 66 + r] = (double)a1L.w;
#pragma unroll
        for (int q = 0; q < 8; ++q) {
            double2 db; db.x = (double)bL[q].x; db.y = (double)bL[q].y;
            *(double2*)&Bs[(4 * q + br0) * 130 + bp0] = db;
        }
        __syncthreads();
        if (k0 + 32 < DD) {
            const int kn = k0 + 32;
            float4 bias0 = *(const float4*)&bd[kn + k8];
            float4 bias1 = *(const float4*)&bd[kn + k8 + 4];
            float4 a0 = *(const float4*)&X[(size_t)(b0 + r) * DD + kn + k8];
            float4 a1 = *(const float4*)&X[(size_t)(b0 + r) * DD + kn + k8 + 4];
            a0.x -= bias0.x; a0.y -= bias0.y; a0.z -= bias0.z; a0.w -= bias0.w;
            a1.x -= bias1.x; a1.y -= bias1.y; a1.z -= bias1.z; a1.w -= bias1.w;
            a0L = a0; a1L = a1;
#pragma unroll
            for (int q = 0; q < 8; ++q)
                bL[q] = *(const float2*)&Ad[(size_t)(kn + 4 * q + br0) * WW + w0 + bp0];
        }
#pragma unroll
        for (int kc = 0; kc < 8; ++kc) {
            const int krow = kc * 4 + (lane >> 4);
            const double* ap = &As[krow * 66 + (lane & 15)];
            const double* bp = &Bs[krow * 130 + wcol * 32 + (lane & 15)];
            double aF[4], bF[2];
#pragma unroll
            for (int m = 0; m < 4; ++m) aF[m] = ap[m * 16];
#pragma unroll
            for (int n = 0; n < 2; ++n) bF[n] = bp[n * 16];
#pragma unroll
            for (int m = 0; m < 4; ++m)
#pragma unroll
                for (int n = 0; n < 2; ++n)
                    acc[m][n] = __builtin_amdgcn_mfma_f64_16x16x4f64(aF[m], bF[n],
                                                                     acc[m][n], 0, 0, 0);
        }
    }

    int pi[4], pj[4];
    mfma_f64_probe(lane, pi, pj);
#pragma unroll
    for (int m = 0; m < 4; ++m) {
#pragma unroll
        for (int v = 0; v < 4; ++v) {
            int row = b0 + m * 16 + pi[v];
#pragma unroll
            for (int n = 0; n < 2; ++n) {
                int col = w0 + wcol * 32 + n * 16 + pj[v];
                Z[(size_t)row * WW + col] = (float)(acc[m][n][v] / (double)nrm[col]);
            }
        }
    }
}

// ---------------------------------------------------------------------------
// R7: Fused MP loop, TWO independent batch rows per block. The per-step
// serial chain (reduce -> data-dependent G-row load ~600-800ns -> update)
// is the mp bottleneck; pairing two rows issues both G-row load streams
// together so one latency covers two rows' work, and the two reduces/updates
// overlap as ILP. Per-row arithmetic identical to the 1-row version ->
// identical selections/outputs. LDS 64.1 KB -> 2 blocks/CU (same 4 rows in
// flight per CU as before at half the per-row step cost).
// ---------------------------------------------------------------------------
__global__ __launch_bounds__(256) void mp_loop2_kernel(const float* __restrict__ z0,
                                                       const float* __restrict__ G,
                                                       int* __restrict__ idxL,
                                                       float* __restrict__ valL) {
    __shared__ __align__(16) float zrow0[WW];   // 32 KB
    __shared__ __align__(16) float zrow1[WW];   // 32 KB
    __shared__ float wv0[4], wv1[4];
    __shared__ int   wi0[4], wi1[4];
    const int b0 = blockIdx.x * 2;
    const int t = threadIdx.x;
    float4* zs0 = (float4*)zrow0;
    float4* zs1 = (float4*)zrow1;

    float best0 = -1.f, best1 = -1.f;
    int bi0 = 0, bi1 = 0;
    unsigned sm0 = 0, sm1 = 0;   // bit j*4+e: slot (t+256*j) element e selected

    {
        const float4* zp0 = (const float4*)(z0 + (size_t)b0 * WW);
        const float4* zp1 = (const float4*)(z0 + (size_t)(b0 + 1) * WW);
#pragma unroll
        for (int j = 0; j < 8; ++j) {
            int slot = t + 256 * j;
            float4 v0 = zp0[slot];
            float4 v1 = zp1[slot];
            zs0[slot] = v0;
            zs1[slot] = v1;
            int w = slot * 4;
            float a0 = fabsf(v0.x), a1 = fabsf(v0.y), a2 = fabsf(v0.z), a3 = fabsf(v0.w);
            if (a0 > best0) { best0 = a0; bi0 = w; }
            if (a1 > best0) { best0 = a1; bi0 = w + 1; }
            if (a2 > best0) { best0 = a2; bi0 = w + 2; }
            if (a3 > best0) { best0 = a3; bi0 = w + 3; }
            float c0 = fabsf(v1.x), c1 = fabsf(v1.y), c2 = fabsf(v1.z), c3 = fabsf(v1.w);
            if (c0 > best1) { best1 = c0; bi1 = w; }
            if (c1 > best1) { best1 = c1; bi1 = w + 1; }
            if (c2 > best1) { best1 = c2; bi1 = w + 2; }
            if (c3 > best1) { best1 = c3; bi1 = w + 3; }
        }
    }

    for (int k = 0; k < KSEL; ++k) {
        float v0 = best0, v1 = best1;
        int i0 = bi0, i1 = bi1;
#pragma unroll
        for (int off = 32; off > 0; off >>= 1) {
            float ov0 = __shfl_xor(v0, off, 64);
            int   oi0 = __shfl_xor(i0, off, 64);
            float ov1 = __shfl_xor(v1, off, 64);
            int   oi1 = __shfl_xor(i1, off, 64);
            if (ov0 > v0 || (ov0 == v0 && oi0 < i0)) { v0 = ov0; i0 = oi0; }
            if (ov1 > v1 || (ov1 == v1 && oi1 < i1)) { v1 = ov1; i1 = oi1; }
        }
        if ((t & 63) == 0) {
            wv0[t >> 6] = v0; wi0[t >> 6] = i0;
            wv1[t >> 6] = v1; wi1[t >> 6] = i1;
        }
        __syncthreads();   // A: partials visible; prev phase's zrow writes visible
        float rv0 = wv0[0], rv1 = wv1[0];
        int   ri0 = wi0[0], ri1 = wi1[0];
#pragma unroll
        for (int q = 1; q < 4; ++q) {
            float q0 = wv0[q], q1 = wv1[q];
            int   j0 = wi0[q], j1 = wi1[q];
            if (q0 > rv0 || (q0 == rv0 && j0 < ri0)) { rv0 = q0; ri0 = j0; }
            if (q1 > rv1 || (q1 == rv1 && j1 < ri1)) { rv1 = q1; ri1 = j1; }
        }
        const int idx0 = ri0, idx1 = ri1;
        const float val0 = zrow0[idx0];   // pre-update value (LDS broadcast)
        const float val1 = zrow1[idx1];
        if (t == 0) {
            idxL[(size_t)b0 * KSEL + k] = idx0;
            valL[(size_t)b0 * KSEL + k] = val0;
            idxL[(size_t)(b0 + 1) * KSEL + k] = idx1;
            valL[(size_t)(b0 + 1) * KSEL + k] = val1;
        }
        if (((idx0 >> 2) & 255) == t)
            sm0 |= 1u << (((idx0 >> 10) << 2) | (idx0 & 3));
        if (((idx1 >> 2) & 255) == t)
            sm1 |= 1u << (((idx1 >> 10) << 2) | (idx1 & 3));
        if (k == KSEL - 1) break;      // final update is dead work
        __syncthreads();   // B: all threads have read vals before zrows change

        best0 = -1.f; bi0 = 0;
        best1 = -1.f; bi1 = 0;
        const float4* gr0 = (const float4*)(G + (size_t)idx0 * WW);
        const float4* gr1 = (const float4*)(G + (size_t)idx1 * WW);
#pragma unroll
        for (int j = 0; j < 8; ++j) {
            int slot = t + 256 * j;
            float4 g0 = gr0[slot];
            float4 g1 = gr1[slot];
            float4 z0v = zs0[slot];
            float4 z1v = zs1[slot];
            unsigned m0 = (sm0 >> (j * 4)) & 0xFu;
            unsigned m1 = (sm1 >> (j * 4)) & 0xFu;
            float n00 = (m0 & 1u) ? 0.f : z0v.x - val0 * g0.x;
            float n01 = (m0 & 2u) ? 0.f : z0v.y - val0 * g0.y;
            float n02 = (m0 & 4u) ? 0.f : z0v.z - val0 * g0.z;
            float n03 = (m0 & 8u) ? 0.f : z0v.w - val0 * g0.w;
            float n10 = (m1 & 1u) ? 0.f : z1v.x - val1 * g1.x;
            float n11 = (m1 & 2u) ? 0.f : z1v.y - val1 * g1.y;
            float n12 = (m1 & 4u) ? 0.f : z1v.z - val1 * g1.z;
            float n13 = (m1 & 8u) ? 0.f : z1v.w - val1 * g1.w;
            zs0[slot] = make_float4(n00, n01, n02, n03);
            zs1[slot] = make_float4(n10, n11, n12, n13);
            int w = slot * 4;
            float a0 = fabsf(n00), a1 = fabsf(n01), a2 = fabsf(n02), a3 = fabsf(n03);
            if (a0 > best0) { best0 = a0; bi0 = w; }
            if (a1 > best0) { best0 = a1; bi0 = w + 1; }
            if (a2 > best0) { best0 = a2; bi0 = w + 2; }
            if (a3 > best0) { best0 = a3; bi0 = w + 3; }
            float c0 = fabsf(n10), c1 = fabsf(n11), c2 = fabsf(n12), c3 = fabsf(n13);
            if (c0 > best1) { best1 = c0; bi1 = w; }
            if (c1 > best1) { best1 = c1; bi1 = w + 1; }
            if (c2 > best1) { best1 = c2; bi1 = w + 2; }
            if (c3 > best1) { best1 = c3; bi1 = w + 3; }
        }
    }
}

// ---------------------------------------------------------------------------
// copy idx/val metadata (d_out staging -> ws), element-wise
// ---------------------------------------------------------------------------
__global__ __launch_bounds__(256) void copy_meta_kernel(const int* __restrict__ si,
                                                        const float* __restrict__ sv,
                                                        int* __restrict__ di,
                                                        float* __restrict__ dv,
                                                        int n) {
    int i = blockIdx.x * 256 + threadIdx.x;
    if (i < n) {
        di[i] = si[i];
        dv[i] = sv[i];
    }
}

// ---------------------------------------------------------------------------
// out[row, :] = bd + sum_k val[b,k] * AdnT[idx[b,k], :]
// ---------------------------------------------------------------------------
__global__ __launch_bounds__(256) void assemble_kernel(const float* __restrict__ AdnT,
                                                       const float* __restrict__ bd,
                                                       const int* __restrict__ idxL,
                                                       const float* __restrict__ valL,
                                                       float* __restrict__ out,
                                                       int rowStart) {
    __shared__ int sidx[KSEL];
    __shared__ float sval[KSEL];
    const int b = blockIdx.x;
    const int row = rowStart + b;
    const int t = threadIdx.x;
    if (t < KSEL) {
        sidx[t] = idxL[(size_t)b * KSEL + t];
        sval[t] = valL[(size_t)b * KSEL + t];
    }
    __syncthreads();
    float acc0 = bd[t];
    float acc1 = bd[t + 256];
    float acc2 = bd[t + 512];
#pragma unroll 4
    for (int k = 0; k < KSEL; ++k) {
        const float* col = AdnT + (size_t)sidx[k] * DD;
        float v = sval[k];
        acc0 += v * col[t];
        acc1 += v * col[t + 256];
        acc2 += v * col[t + 512];
    }
    out[(size_t)row * DD + t] = acc0;
    out[(size_t)row * DD + t + 256] = acc1;
    out[(size_t)row * DD + t + 512] = acc2;
}

// ---------------------------------------------------------------------------
extern "C" void kernel_launch(void* const* d_in, const int* in_sizes, int n_in,
                              void* d_out, int out_size, void* d_ws, size_t ws_size,
                              hipStream_t stream) {
    const float* x  = (const float*)d_in[0];   // [B, D]
    const float* Ad = (const float*)d_in[1];   // [D, W]
    const float* bd = (const float*)d_in[2];   // [1, D]
    float* out = (float*)d_out;                // [B, D]

    const size_t ADNT_B = (size_t)WW * DD * 4;        // 25,165,824
    const size_t NRM_B  = (size_t)WW * 4;             // 32,768
    const size_t IDX_B  = (size_t)BBATCH * KSEL * 4;  // 1,048,576
    const size_t VAL_B  = IDX_B;
    const size_t G_B    = (size_t)WW * WW * 4;        // 268,435,456 (= 256 MiB)
    const size_t ZROW_B = (size_t)WW * 4;             // 32,768
    const size_t A_MIN  = ADNT_B + NRM_B + IDX_B + VAL_B + G_B + 128 * ZROW_B;

    if (ws_size >= A_MIN) {
        // ---------------- Layout A: everything in ws ----------------
        char* p = (char*)d_ws;
        float* AdnT = (float*)p;  p += ADNT_B;
        float* nrm  = (float*)p;  p += NRM_B;
        int*   idxL = (int*)p;    p += IDX_B;
        float* valL = (float*)p;  p += VAL_B;
        float* G    = (float*)p;  p += G_B;
        float* z    = (float*)p;
        size_t z_avail = ws_size - (ADNT_B + NRM_B + IDX_B + VAL_B + G_B);
        int chunk = (int)((z_avail / ZROW_B) / 128) * 128;
        if (chunk > BBATCH) chunk = BBATCH;

        colnorm_kernel<<<WW / 256, 256, 0, stream>>>(Ad, nrm);
        gram_mfma_f64_kernel<<<dim3(WW / 64, WW / 128), 256, 0, stream>>>(Ad, nrm, G);
        mirror_kernel<<<dim3(WW / 64, WW / 64), 256, 0, stream>>>(G);
        for (int r0 = 0; r0 < BBATCH; r0 += chunk) {
            int rows = (BBATCH - r0 < chunk) ? (BBATCH - r0) : chunk;
            z_mfma_f64_kernel<<<dim3(WW / 128, rows / 64), 256, 0, stream>>>(
                x + (size_t)r0 * DD, Ad, bd, nrm, z);
            mp_loop2_kernel<<<rows / 2, 256, 0, stream>>>(
                z, G, idxL + (size_t)r0 * KSEL, valL + (size_t)r0 * KSEL);
        }
        transpose_scale_kernel<<<dim3(WW / 32, DD / 32), dim3(32, 8), 0, stream>>>(Ad, nrm, AdnT);
        assemble_kernel<<<BBATCH, 256, 0, stream>>>(AdnT, bd, idxL, valL, out, 0);
    } else if (ws_size >= G_B) {
        // ---------------- Layout B: ws = G only; scratch in d_out ----------------
        // d_out carve (25,165,824 B total):
        //   [0 .. 20,971,520)          z chunks (512 rows x 32 KB used)
        //   [20,971,520 .. 21,004,288) nrm (32 KB)
        //   [23,068,672 .. 24,117,248) idxL [B,32]
        //   [24,117,248 .. 25,165,824) valL [B,32]
        float* G    = (float*)d_ws;
        char*  ob   = (char*)d_out;
        float* z    = (float*)ob;
        float* nrm  = (float*)(ob + 20971520);
        int*   idxL = (int*)(ob + 23068672);
        float* valL = (float*)(ob + 24117248);
        // after MP loops, G is dead -> reuse ws:
        float* AdnT = (float*)d_ws;
        int*   idx2 = (int*)((char*)d_ws + ADNT_B);
        float* val2 = (float*)((char*)d_ws + ADNT_B + IDX_B);
        const int chunk = 512;   // z grid (64, 8) -> 512 blocks

        colnorm_kernel<<<WW / 256, 256, 0, stream>>>(Ad, nrm);
        gram_mfma_f64_kernel<<<dim3(WW / 64, WW / 128), 256, 0, stream>>>(Ad, nrm, G);
        mirror_kernel<<<dim3(WW / 64, WW / 64), 256, 0, stream>>>(G);
        for (int r0 = 0; r0 < BBATCH; r0 += chunk) {
            int rows = (BBATCH - r0 < chunk) ? (BBATCH - r0) : chunk;
            z_mfma_f64_kernel<<<dim3(WW / 128, rows / 64), 256, 0, stream>>>(
                x + (size_t)r0 * DD, Ad, bd, nrm, z);
            mp_loop2_kernel<<<rows / 2, 256, 0, stream>>>(
                z, G, idxL + (size_t)r0 * KSEL, valL + (size_t)r0 * KSEL);
        }
        {
            int n = BBATCH * KSEL;
            copy_meta_kernel<<<(n + 255) / 256, 256, 0, stream>>>(idxL, valL, idx2, val2, n);
        }
        transpose_scale_kernel<<<dim3(WW / 32, DD / 32), dim3(32, 8), 0, stream>>>(Ad, nrm, AdnT);
        assemble_kernel<<<BBATCH, 256, 0, stream>>>(AdnT, bd, idx2, val2, out, 0);
    }
    // else: ws too small for any fp32-G plan -> leave output zeroed (clean fail)
}

// Round 8
// 4781.343 us; speedup vs baseline: 1.1161x; 1.1161x over previous
//
#include <hip/hip_runtime.h>
#include <cstddef>

// Problem constants (fixed by the reference)
static const int WW = 8192;     // width (atoms)
static const int DD = 768;      // input dim
static const int BBATCH = 8192; // batch
static const int KSEL = 32;     // MP steps

typedef double f64x4 __attribute__((ext_vector_type(4)));

// ---------------------------------------------------------------------------
// Runtime probe of the v_mfma_f64_16x16x4 D-fragment wiring (HW-verified in
// R2: hardcoded map failed, probe-derived map passes). Assumes only the INPUT
// gather (i=lane%16, k=lane/16 for A; j=lane%16, k=lane/16 for B). Decodes
// the (lane,reg)->(i,j) output map for ANY wiring; clamped so a broken
// assumption cannot write OOB. Called at epilogue only.
// ---------------------------------------------------------------------------
__device__ inline void mfma_f64_probe(int lane, int* pi, int* pj) {
    f64x4 z0{0.0, 0.0, 0.0, 0.0};
    f64x4 d1 = __builtin_amdgcn_mfma_f64_16x16x4f64((double)lane, 1.0, z0, 0, 0, 0);
    f64x4 d2 = __builtin_amdgcn_mfma_f64_16x16x4f64(1.0, (double)lane, z0, 0, 0, 0);
#pragma unroll
    for (int v = 0; v < 4; ++v) {
        pi[v] = (((int)d1[v] - 96) >> 2) & 15;
        pj[v] = (((int)d2[v] - 96) >> 2) & 15;
    }
}

// ---------------------------------------------------------------------------
// column norms of Ad [D, W] -> nrm[W] = max(||Ad[:,w]||, 1e-8), fp64 accumulate
// ---------------------------------------------------------------------------
__global__ __launch_bounds__(256) void colnorm_kernel(const float* __restrict__ Ad,
                                                      float* __restrict__ nrm) {
    int w = blockIdx.x * 256 + threadIdx.x;
    double s = 0.0;
    for (int d = 0; d < DD; ++d) {
        double v = (double)Ad[(size_t)d * WW + w];
        s += v * v;
    }
    nrm[w] = fmaxf((float)sqrt(s), 1e-8f);
}

// ---------------------------------------------------------------------------
// AdnT[w, d] = Ad[d, w] / nrm[w]   (LDS tiled transpose, 32x32)
// ---------------------------------------------------------------------------
__global__ __launch_bounds__(256) void transpose_scale_kernel(const float* __restrict__ Ad,
                                                              const float* __restrict__ nrm,
                                                              float* __restrict__ AdnT) {
    __shared__ float tile[32][33];
    int wb = blockIdx.x * 32;
    int db = blockIdx.y * 32;
    int tx = threadIdx.x;   // 0..31
    int ty = threadIdx.y;   // 0..7
    for (int i = ty; i < 32; i += 8)
        tile[i][tx] = Ad[(size_t)(db + i) * WW + (wb + tx)];
    __syncthreads();
    for (int i = ty; i < 32; i += 8)
        AdnT[(size_t)(wb + i) * DD + (db + tx)] = tile[tx][i] / nrm[wb + i];
}

// ---------------------------------------------------------------------------
// Gram via f64 MFMA (BK=16 config = measured best: 1088-1095 us, ~66% util).
// 128x64 block, 4 waves 2x2, each wave 64x32 = 4x2 tiles, 25 KiB LDS.
// Upper blocks only (bx >= 2*by); mirror fills strict-lower tiles.
// ---------------------------------------------------------------------------
__global__ __launch_bounds__(256, 2) void gram_mfma_f64_kernel(const float* __restrict__ Ad,
                                                               const float* __restrict__ nrm,
                                                               float* __restrict__ G) {
    const int bx = blockIdx.x, by = blockIdx.y;
    if (bx < 2 * by) return;   // block entirely strictly-lower -> skip (mirror fills)
    __shared__ __align__(16) double As[16 * 130];   // As[k][i], i=0..127
    __shared__ __align__(16) double Bs[16 * 66];    // Bs[k][j], j=0..63
    const int tid = threadIdx.x;
    const int lane = tid & 63;
    const int wv = tid >> 6;        // wave 0..3
    const int wr = wv >> 1;         // 0..1 row half (64 rows)
    const int wc = wv & 1;          // 0..1 col half (32 cols)
    const int i0 = by * 128;
    const int j0 = bx * 64;
    const int ar0 = tid >> 6;        // 0..3
    const int ap0 = (tid & 63) * 2;  // 0..126
    const int brow = tid >> 5;       // 0..7
    const int bpos = (tid & 31) * 2; // 0..62

    f64x4 acc[4][2];
#pragma unroll
    for (int m = 0; m < 4; ++m)
#pragma unroll
        for (int n = 0; n < 2; ++n)
            acc[m][n] = f64x4{0.0, 0.0, 0.0, 0.0};

    float2 aL[4], bl0, bl1;
#pragma unroll
    for (int q = 0; q < 4; ++q)
        aL[q] = *(const float2*)&Ad[(size_t)(4 * q + ar0) * WW + i0 + ap0];
    bl0 = *(const float2*)&Ad[(size_t)(brow) * WW + j0 + bpos];
    bl1 = *(const float2*)&Ad[(size_t)(8 + brow) * WW + j0 + bpos];

    for (int k0 = 0; k0 < DD; k0 += 16) {
        __syncthreads();   // previous iteration's LDS reads done
#pragma unroll
        for (int q = 0; q < 4; ++q) {
            double2 da; da.x = (double)aL[q].x; da.y = (double)aL[q].y;
            *(double2*)&As[(4 * q + ar0) * 130 + ap0] = da;
        }
        {
            double2 d0; d0.x = (double)bl0.x; d0.y = (double)bl0.y;
            double2 d1; d1.x = (double)bl1.x; d1.y = (double)bl1.y;
            *(double2*)&Bs[brow * 66 + bpos] = d0;
            *(double2*)&Bs[(8 + brow) * 66 + bpos] = d1;
        }
        __syncthreads();
        if (k0 + 16 < DD) {   // prefetch next panel; latency hides under MFMAs
#pragma unroll
            for (int q = 0; q < 4; ++q)
                aL[q] = *(const float2*)&Ad[(size_t)(k0 + 16 + 4 * q + ar0) * WW + i0 + ap0];
            bl0 = *(const float2*)&Ad[(size_t)(k0 + 16 + brow) * WW + j0 + bpos];
            bl1 = *(const float2*)&Ad[(size_t)(k0 + 24 + brow) * WW + j0 + bpos];
        }
#pragma unroll
        for (int kc = 0; kc < 4; ++kc) {
            const int krow = kc * 4 + (lane >> 4);
            const double* ap = &As[krow * 130 + wr * 64 + (lane & 15)];
            const double* bp = &Bs[krow * 66 + wc * 32 + (lane & 15)];
            double aF[4], bF[2];
#pragma unroll
            for (int m = 0; m < 4; ++m) aF[m] = ap[m * 16];
#pragma unroll
            for (int n = 0; n < 2; ++n) bF[n] = bp[n * 16];
#pragma unroll
            for (int m = 0; m < 4; ++m)
#pragma unroll
                for (int n = 0; n < 2; ++n)
                    acc[m][n] = __builtin_amdgcn_mfma_f64_16x16x4f64(aF[m], bF[n],
                                                                     acc[m][n], 0, 0, 0);
        }
    }

    int pi[4], pj[4];
    mfma_f64_probe(lane, pi, pj);
#pragma unroll
    for (int m = 0; m < 4; ++m) {
#pragma unroll
        for (int v = 0; v < 4; ++v) {
            int row = i0 + wr * 64 + m * 16 + pi[v];
            double inv_i = 1.0 / (double)nrm[row];
#pragma unroll
            for (int n = 0; n < 2; ++n) {
                int col = j0 + wc * 32 + n * 16 + pj[v];
                G[(size_t)row * WW + col] = (float)(acc[m][n][v] * inv_i / (double)nrm[col]);
            }
        }
    }
}

// ---------------------------------------------------------------------------
// mirror: G[j,i] = G[i,j] for strict-upper 64x64 tiles
// ---------------------------------------------------------------------------
__global__ __launch_bounds__(256) void mirror_kernel(float* __restrict__ G) {
    const int ti = blockIdx.y;
    const int tj = blockIdx.x;
    if (tj <= ti) return;
    __shared__ float tile[64][65];
    const int t = threadIdx.x;
    const int c4 = (t & 15) * 4;   // 0..60
    const int r  = t >> 4;         // 0..15
#pragma unroll
    for (int rr = r; rr < 64; rr += 16) {
        float4 v = *(const float4*)&G[(size_t)(ti * 64 + rr) * WW + tj * 64 + c4];
        tile[rr][c4 + 0] = v.x;
        tile[rr][c4 + 1] = v.y;
        tile[rr][c4 + 2] = v.z;
        tile[rr][c4 + 3] = v.w;
    }
    __syncthreads();
#pragma unroll
    for (int rr = r; rr < 64; rr += 16) {
        float4 v = make_float4(tile[c4 + 0][rr], tile[c4 + 1][rr],
                               tile[c4 + 2][rr], tile[c4 + 3][rr]);
        *(float4*)&G[(size_t)(tj * 64 + rr) * WW + ti * 64 + c4] = v;
    }
}

// ---------------------------------------------------------------------------
// z via f64 MFMA (R4 config): Z[b,w] = (sum_d (X[b,d]-bd[d]) * Ad[d,w]) / nrm[w]
// 64x128 block, 4 waves (1x4), each wave 4x2 tiles, BK=32.
// ---------------------------------------------------------------------------
__global__ __launch_bounds__(256, 2) void z_mfma_f64_kernel(const float* __restrict__ X,
                                                            const float* __restrict__ Ad,
                                                            const float* __restrict__ bd,
                                                            const float* __restrict__ nrm,
                                                            float* __restrict__ Z) {
    __shared__ __align__(16) double As[32 * 66];    // As[k][b], b=0..63
    __shared__ __align__(16) double Bs[32 * 130];   // Bs[k][w], w=0..127
    const int tid = threadIdx.x;
    const int lane = tid & 63;
    const int wcol = tid >> 6;      // wave 0..3 -> 32-col group
    const int b0 = blockIdx.y * 64;
    const int w0 = blockIdx.x * 128;
    const int r  = tid >> 2;        // 0..63 batch row (A staging)
    const int k8 = (tid & 3) * 8;   // k offset 0..24
    const int br0 = tid >> 6;
    const int bp0 = (tid & 63) * 2;

    f64x4 acc[4][2];
#pragma unroll
    for (int m = 0; m < 4; ++m)
#pragma unroll
        for (int n = 0; n < 2; ++n)
            acc[m][n] = f64x4{0.0, 0.0, 0.0, 0.0};

    float4 a0L, a1L; float2 bL[8];
    {
        float4 bias0 = *(const float4*)&bd[k8];
        float4 bias1 = *(const float4*)&bd[k8 + 4];
        float4 a0 = *(const float4*)&X[(size_t)(b0 + r) * DD + k8];
        float4 a1 = *(const float4*)&X[(size_t)(b0 + r) * DD + k8 + 4];
        a0.x -= bias0.x; a0.y -= bias0.y; a0.z -= bias0.z; a0.w -= bias0.w;
        a1.x -= bias1.x; a1.y -= bias1.y; a1.z -= bias1.z; a1.w -= bias1.w;
        a0L = a0; a1L = a1;
#pragma unroll
        for (int q = 0; q < 8; ++q)
            bL[q] = *(const float2*)&Ad[(size_t)(4 * q + br0) * WW + w0 + bp0];
    }

    for (int k0 = 0; k0 < DD; k0 += 32) {
        __syncthreads();   // previous iteration's LDS reads done
        As[(k8 + 0) * 66 + r] = (double)a0L.x;
        As[(k8 + 1) * 66 + r] = (double)a0L.y;
        As[(k8 + 2) * 66 + r] = (double)a0L.z;
        As[(k8 + 3) * 66 + r] = (double)a0L.w;
        As[(k8 + 4) * 66 + r] = (double)a1L.x;
        As[(k8 + 5) * 66 + r] = (double)a1L.y;
        As[(k8 + 6) * 66 + r] = (double)a1L.z;
        As[(k8 + 7) * 66 + r] = (double)a1L.w;
#pragma unroll
        for (int q = 0; q < 8; ++q) {
            double2 db; db.x = (double)bL[q].x; db.y = (double)bL[q].y;
            *(double2*)&Bs[(4 * q + br0) * 130 + bp0] = db;
        }
        __syncthreads();
        if (k0 + 32 < DD) {
            const int kn = k0 + 32;
            float4 bias0 = *(const float4*)&bd[kn + k8];
            float4 bias1 = *(const float4*)&bd[kn + k8 + 4];
            float4 a0 = *(const float4*)&X[(size_t)(b0 + r) * DD + kn + k8];
            float4 a1 = *(const float4*)&X[(size_t)(b0 + r) * DD + kn + k8 + 4];
            a0.x -= bias0.x; a0.y -= bias0.y; a0.z -= bias0.z; a0.w -= bias0.w;
            a1.x -= bias1.x; a1.y -= bias1.y; a1.z -= bias1.z; a1.w -= bias1.w;
            a0L = a0; a1L = a1;
#pragma unroll
            for (int q = 0; q < 8; ++q)
                bL[q] = *(const float2*)&Ad[(size_t)(kn + 4 * q + br0) * WW + w0 + bp0];
        }
#pragma unroll
        for (int kc = 0; kc < 8; ++kc) {
            const int krow = kc * 4 + (lane >> 4);
            const double* ap = &As[krow * 66 + (lane & 15)];
            const double* bp = &Bs[krow * 130 + wcol * 32 + (lane & 15)];
            double aF[4], bF[2];
#pragma unroll
            for (int m = 0; m < 4; ++m) aF[m] = ap[m * 16];
#pragma unroll
            for (int n = 0; n < 2; ++n) bF[n] = bp[n * 16];
#pragma unroll
            for (int m = 0; m < 4; ++m)
#pragma unroll
                for (int n = 0; n < 2; ++n)
                    acc[m][n] = __builtin_amdgcn_mfma_f64_16x16x4f64(aF[m], bF[n],
                                                                     acc[m][n], 0, 0, 0);
        }
    }

    int pi[4], pj[4];
    mfma_f64_probe(lane, pi, pj);
#pragma unroll
    for (int m = 0; m < 4; ++m) {
#pragma unroll
        for (int v = 0; v < 4; ++v) {
            int row = b0 + m * 16 + pi[v];
#pragma unroll
            for (int n = 0; n < 2; ++n) {
                int col = w0 + wcol * 32 + n * 16 + pj[v];
                Z[(size_t)row * WW + col] = (float)(acc[m][n][v] / (double)nrm[col]);
            }
        }
    }
}

// ---------------------------------------------------------------------------
// R8: MP loop with REGISTER-resident z row (one row per block, as R4).
// Each thread owns 32 z values (8 float4s, slot = t + 256*j). Deletes the
// 8 ds_read_b128 + 8 ds_write_b128 per thread per step from the serial
// chain; LDS shrinks 32.8 KB -> ~48 B. val broadcast: the owner thread
// extracts its element with a statically-unrolled select (no dynamic reg
// indexing -> no scratch) and publishes via one LDS scalar. Barrier count
// unchanged (2/step); selection arithmetic bit-identical to R4.
// ---------------------------------------------------------------------------
__global__ __launch_bounds__(256) void mp_loop_reg_kernel(const float* __restrict__ z0,
                                                          const float* __restrict__ G,
                                                          int* __restrict__ idxL,
                                                          float* __restrict__ valL) {
    __shared__ float wv[4];
    __shared__ int   wi[4];
    __shared__ float sval;
    const int b = blockIdx.x;
    const int t = threadIdx.x;

    float4 zr[8];           // register-resident z slice
    float best = -1.f;
    int bidx = 0;
    unsigned selmask = 0;   // bit j*4+e: slot (t+256*j) element e is selected

    {
        const float4* zp = (const float4*)(z0 + (size_t)b * WW);
#pragma unroll
        for (int j = 0; j < 8; ++j) {
            int slot = t + 256 * j;
            float4 v = zp[slot];
            zr[j] = v;
            int w = slot * 4;
            float a0 = fabsf(v.x), a1 = fabsf(v.y), a2 = fabsf(v.z), a3 = fabsf(v.w);
            if (a0 > best) { best = a0; bidx = w; }
            if (a1 > best) { best = a1; bidx = w + 1; }
            if (a2 > best) { best = a2; bidx = w + 2; }
            if (a3 > best) { best = a3; bidx = w + 3; }
        }
    }

    for (int k = 0; k < KSEL; ++k) {
        float v = best;
        int i = bidx;
#pragma unroll
        for (int off = 32; off > 0; off >>= 1) {
            float ov = __shfl_xor(v, off, 64);
            int   oi = __shfl_xor(i, off, 64);
            if (ov > v || (ov == v && oi < i)) { v = ov; i = oi; }
        }
        if ((t & 63) == 0) { wv[t >> 6] = v; wi[t >> 6] = i; }
        __syncthreads();   // A: wave partials visible; prev step's sval reads done
        float rv = wv[0];
        int   ri = wi[0];
#pragma unroll
        for (int q = 1; q < 4; ++q) {
            float qv = wv[q];
            int   qi = wi[q];
            if (qv > rv || (qv == rv && qi < ri)) { rv = qv; ri = qi; }
        }
        const int idx = ri;
        // owner publishes the pre-update value (static unroll, no scratch)
        if (((idx >> 2) & 255) == t) {
            float myv = 0.f;
#pragma unroll
            for (int j = 0; j < 8; ++j) {
                if ((idx >> 10) == j) {
                    float4 q = zr[j];
                    int e = idx & 3;
                    myv = (e == 0) ? q.x : (e == 1) ? q.y : (e == 2) ? q.z : q.w;
                }
            }
            sval = myv;
            selmask |= 1u << (((idx >> 10) << 2) | (idx & 3));
        }
        __syncthreads();   // B: sval visible
        const float val = sval;
        if (t == 0) {
            idxL[(size_t)b * KSEL + k] = idx;
            valL[(size_t)b * KSEL + k] = val;
        }
        if (k == KSEL - 1) break;      // final update is dead work

        best = -1.f;
        bidx = 0;
        const float4* gr = (const float4*)(G + (size_t)idx * WW);
#pragma unroll
        for (int j = 0; j < 8; ++j) {
            int slot = t + 256 * j;
            float4 g = gr[slot];
            float4 z = zr[j];
            unsigned m = (selmask >> (j * 4)) & 0xFu;
            float n0 = (m & 1u) ? 0.f : z.x - val * g.x;
            float n1 = (m & 2u) ? 0.f : z.y - val * g.y;
            float n2 = (m & 4u) ? 0.f : z.z - val * g.z;
            float n3 = (m & 8u) ? 0.f : z.w - val * g.w;
            zr[j] = make_float4(n0, n1, n2, n3);
            int w = slot * 4;
            float a0 = fabsf(n0), a1 = fabsf(n1), a2 = fabsf(n2), a3 = fabsf(n3);
            if (a0 > best) { best = a0; bidx = w; }
            if (a1 > best) { best = a1; bidx = w + 1; }
            if (a2 > best) { best = a2; bidx = w + 2; }
            if (a3 > best) { best = a3; bidx = w + 3; }
        }
    }
}

// ---------------------------------------------------------------------------
// copy idx/val metadata (d_out staging -> ws), element-wise
// ---------------------------------------------------------------------------
__global__ __launch_bounds__(256) void copy_meta_kernel(const int* __restrict__ si,
                                                        const float* __restrict__ sv,
                                                        int* __restrict__ di,
                                                        float* __restrict__ dv,
                                                        int n) {
    int i = blockIdx.x * 256 + threadIdx.x;
    if (i < n) {
        di[i] = si[i];
        dv[i] = sv[i];
    }
}

// ---------------------------------------------------------------------------
// out[row, :] = bd + sum_k val[b,k] * AdnT[idx[b,k], :]
// ---------------------------------------------------------------------------
__global__ __launch_bounds__(256) void assemble_kernel(const float* __restrict__ AdnT,
                                                       const float* __restrict__ bd,
                                                       const int* __restrict__ idxL,
                                                       const float* __restrict__ valL,
                                                       float* __restrict__ out,
                                                       int rowStart) {
    __shared__ int sidx[KSEL];
    __shared__ float sval[KSEL];
    const int b = blockIdx.x;
    const int row = rowStart + b;
    const int t = threadIdx.x;
    if (t < KSEL) {
        sidx[t] = idxL[(size_t)b * KSEL + t];
        sval[t] = valL[(size_t)b * KSEL + t];
    }
    __syncthreads();
    float acc0 = bd[t];
    float acc1 = bd[t + 256];
    float acc2 = bd[t + 512];
#pragma unroll 4
    for (int k = 0; k < KSEL; ++k) {
        const float* col = AdnT + (size_t)sidx[k] * DD;
        float v = sval[k];
        acc0 += v * col[t];
        acc1 += v * col[t + 256];
        acc2 += v * col[t + 512];
    }
    out[(size_t)row * DD + t] = acc0;
    out[(size_t)row * DD + t + 256] = acc1;
    out[(size_t)row * DD + t + 512] = acc2;
}

// ---------------------------------------------------------------------------
extern "C" void kernel_launch(void* const* d_in, const int* in_sizes, int n_in,
                              void* d_out, int out_size, void* d_ws, size_t ws_size,
                              hipStream_t stream) {
    const float* x  = (const float*)d_in[0];   // [B, D]
    const float* Ad = (const float*)d_in[1];   // [D, W]
    const float* bd = (const float*)d_in[2];   // [1, D]
    float* out = (float*)d_out;                // [B, D]

    const size_t ADNT_B = (size_t)WW * DD * 4;        // 25,165,824
    const size_t NRM_B  = (size_t)WW * 4;             // 32,768
    const size_t IDX_B  = (size_t)BBATCH * KSEL * 4;  // 1,048,576
    const size_t VAL_B  = IDX_B;
    const size_t G_B    = (size_t)WW * WW * 4;        // 268,435,456 (= 256 MiB)
    const size_t ZROW_B = (size_t)WW * 4;             // 32,768
    const size_t A_MIN  = ADNT_B + NRM_B + IDX_B + VAL_B + G_B + 128 * ZROW_B;

    if (ws_size >= A_MIN) {
        // ---------------- Layout A: everything in ws ----------------
        char* p = (char*)d_ws;
        float* AdnT = (float*)p;  p += ADNT_B;
        float* nrm  = (float*)p;  p += NRM_B;
        int*   idxL = (int*)p;    p += IDX_B;
        float* valL = (float*)p;  p += VAL_B;
        float* G    = (float*)p;  p += G_B;
        float* z    = (float*)p;
        size_t z_avail = ws_size - (ADNT_B + NRM_B + IDX_B + VAL_B + G_B);
        int chunk = (int)((z_avail / ZROW_B) / 128) * 128;
        if (chunk > BBATCH) chunk = BBATCH;

        colnorm_kernel<<<WW / 256, 256, 0, stream>>>(Ad, nrm);
        gram_mfma_f64_kernel<<<dim3(WW / 64, WW / 128), 256, 0, stream>>>(Ad, nrm, G);
        mirror_kernel<<<dim3(WW / 64, WW / 64), 256, 0, stream>>>(G);
        for (int r0 = 0; r0 < BBATCH; r0 += chunk) {
            int rows = (BBATCH - r0 < chunk) ? (BBATCH - r0) : chunk;
            z_mfma_f64_kernel<<<dim3(WW / 128, rows / 64), 256, 0, stream>>>(
                x + (size_t)r0 * DD, Ad, bd, nrm, z);
            mp_loop_reg_kernel<<<rows, 256, 0, stream>>>(
                z, G, idxL + (size_t)r0 * KSEL, valL + (size_t)r0 * KSEL);
        }
        transpose_scale_kernel<<<dim3(WW / 32, DD / 32), dim3(32, 8), 0, stream>>>(Ad, nrm, AdnT);
        assemble_kernel<<<BBATCH, 256, 0, stream>>>(AdnT, bd, idxL, valL, out, 0);
    } else if (ws_size >= G_B) {
        // ---------------- Layout B: ws = G only; scratch in d_out ----------------
        // d_out carve (25,165,824 B total):
        //   [0 .. 20,971,520)          z chunks (640 rows x 32 KB)
        //   [20,971,520 .. 21,004,288) nrm (32 KB)
        //   [23,068,672 .. 24,117,248) idxL [B,32]
        //   [24,117,248 .. 25,165,824) valL [B,32]
        float* G    = (float*)d_ws;
        char*  ob   = (char*)d_out;
        float* z    = (float*)ob;
        float* nrm  = (float*)(ob + 20971520);
        int*   idxL = (int*)(ob + 23068672);
        float* valL = (float*)(ob + 24117248);
        // after MP loops, G is dead -> reuse ws:
        float* AdnT = (float*)d_ws;
        int*   idx2 = (int*)((char*)d_ws + ADNT_B);
        float* val2 = (float*)((char*)d_ws + ADNT_B + IDX_B);
        const int chunk = 640;   // full d_out z capacity -> 2.5 blocks/CU

        colnorm_kernel<<<WW / 256, 256, 0, stream>>>(Ad, nrm);
        gram_mfma_f64_kernel<<<dim3(WW / 64, WW / 128), 256, 0, stream>>>(Ad, nrm, G);
        mirror_kernel<<<dim3(WW / 64, WW / 64), 256, 0, stream>>>(G);
        for (int r0 = 0; r0 < BBATCH; r0 += chunk) {
            int rows = (BBATCH - r0 < chunk) ? (BBATCH - r0) : chunk;
            z_mfma_f64_kernel<<<dim3(WW / 128, rows / 64), 256, 0, stream>>>(
                x + (size_t)r0 * DD, Ad, bd, nrm, z);
            mp_loop_reg_kernel<<<rows, 256, 0, stream>>>(
                z, G, idxL + (size_t)r0 * KSEL, valL + (size_t)r0 * KSEL);
        }
        {
            int n = BBATCH * KSEL;
            copy_meta_kernel<<<(n + 255) / 256, 256, 0, stream>>>(idxL, valL, idx2, val2, n);
        }
        transpose_scale_kernel<<<dim3(WW / 32, DD / 32), dim3(32, 8), 0, stream>>>(Ad, nrm, AdnT);
        assemble_kernel<<<BBATCH, 256, 0, stream>>>(AdnT, bd, idx2, val2, out, 0);
    }
    // else: ws too small for any fp32-G plan -> leave output zeroed (clean fail)
}

// Round 9
// 3991.522 us; speedup vs baseline: 1.3370x; 1.1979x over previous
//
#include <hip/hip_runtime.h>
#include <cstddef>

// Problem constants (fixed by the reference)
static const int WW = 8192;     // width (atoms)
static const int DD = 768;      // input dim
static const int BBATCH = 8192; // batch
static const int KSEL = 32;     // MP steps

// ---------------------------------------------------------------------------
// column norms of Ad [D, W] -> nrm[W] = max(||Ad[:,w]||, 1e-8), fp64 accumulate
// (unchanged: nrm values bitwise-identical to all prior passing rounds)
// ---------------------------------------------------------------------------
__global__ __launch_bounds__(256) void colnorm_kernel(const float* __restrict__ Ad,
                                                      float* __restrict__ nrm) {
    int w = blockIdx.x * 256 + threadIdx.x;
    double s = 0.0;
    for (int d = 0; d < DD; ++d) {
        double v = (double)Ad[(size_t)d * WW + w];
        s += v * v;
    }
    nrm[w] = fmaxf((float)sqrt(s), 1e-8f);
}

// ---------------------------------------------------------------------------
// AdnT[w, d] = Ad[d, w] / nrm[w]   (LDS tiled transpose, 32x32)
// ---------------------------------------------------------------------------
__global__ __launch_bounds__(256) void transpose_scale_kernel(const float* __restrict__ Ad,
                                                              const float* __restrict__ nrm,
                                                              float* __restrict__ AdnT) {
    __shared__ float tile[32][33];
    int wb = blockIdx.x * 32;
    int db = blockIdx.y * 32;
    int tx = threadIdx.x;   // 0..31
    int ty = threadIdx.y;   // 0..7
    for (int i = ty; i < 32; i += 8)
        tile[i][tx] = Ad[(size_t)(db + i) * WW + (wb + tx)];
    __syncthreads();
    for (int i = ty; i < 32; i += 8)
        AdnT[(size_t)(wb + i) * DD + (db + tx)] = tile[tx][i] / nrm[wb + i];
}

// ---------------------------------------------------------------------------
// R9: Gram in f32 VECTOR math (157 TF pipe = 2x the 78.6 TF f64 MFMA pipe).
// Structure = round-0's proven gram_tn_f64 (1373 us @ 60.8% VALUBusy as f64;
// FMA-issue cycles halve in f32, LDS bytes halve). 128x64 tile, BK=16,
// 256 threads, 8x4 f32 microtile. As stride 132 (f32 float4 alignment).
// Epilogue normalization kept in f64 (one div per output, exact as before).
// Upper-region blocks only (bx >= 2*by); mirror fills strict-lower tiles.
// Reference is f32, so f32 accumulation error (~1e-6 rel) is the same scale
// as the f32-rounding gap the passing f64 kernel already tolerates.
// ---------------------------------------------------------------------------
__global__ __launch_bounds__(256) void gram_tn_f32_kernel(const float* __restrict__ Ad,
                                                          const float* __restrict__ nrm,
                                                          float* __restrict__ G) {
    const int bx = blockIdx.x, by = blockIdx.y;
    if (bx < 2 * by) return;   // block entirely strictly-lower -> skip
    __shared__ __align__(16) float As[16 * 132];   // As[k][i], i=0..127 (pad 4)
    __shared__ __align__(16) float Bs[16 * 66];    // Bs[k][j], j=0..63  (pad 2)
    const int tid = threadIdx.x;
    const int tx = tid & 15;         // 0..15 (col group)
    const int ty = tid >> 4;         // 0..15 (row group)
    const int i0 = by * 128;
    const int j0 = bx * 64;
    const int ar0 = tid >> 6;        // 0..3
    const int ap0 = (tid & 63) * 2;  // 0..126
    const int brow = tid >> 5;       // 0..7
    const int bpos = (tid & 31) * 2; // 0..62

    float acc[8][4];
#pragma unroll
    for (int i = 0; i < 8; ++i)
#pragma unroll
        for (int j = 0; j < 4; ++j) acc[i][j] = 0.0f;

    for (int k0 = 0; k0 < DD; k0 += 16) {
        float2 aL[4];
#pragma unroll
        for (int q = 0; q < 4; ++q)
            aL[q] = *(const float2*)&Ad[(size_t)(k0 + 4 * q + ar0) * WW + i0 + ap0];
        float2 bl0 = *(const float2*)&Ad[(size_t)(k0 + brow) * WW + j0 + bpos];
        float2 bl1 = *(const float2*)&Ad[(size_t)(k0 + 8 + brow) * WW + j0 + bpos];
        __syncthreads();   // previous iteration's LDS reads done
#pragma unroll
        for (int q = 0; q < 4; ++q)
            *(float2*)&As[(4 * q + ar0) * 132 + ap0] = aL[q];
        *(float2*)&Bs[brow * 66 + bpos] = bl0;
        *(float2*)&Bs[(8 + brow) * 66 + bpos] = bl1;
        __syncthreads();

#pragma unroll
        for (int kk = 0; kk < 16; ++kk) {
            const float* arw = &As[kk * 132];
            const float* bb = &Bs[kk * 66];
            float4 a0 = *(const float4*)&arw[ty * 4];        // broadcast reads
            float4 a1 = *(const float4*)&arw[64 + ty * 4];
            float av[8] = {a0.x, a0.y, a0.z, a0.w, a1.x, a1.y, a1.z, a1.w};
            float bv[4] = {bb[tx], bb[16 + tx], bb[32 + tx], bb[48 + tx]};
#pragma unroll
            for (int i = 0; i < 8; ++i)
#pragma unroll
                for (int j = 0; j < 4; ++j) acc[i][j] += av[i] * bv[j];
        }
    }

#pragma unroll
    for (int band = 0; band < 2; ++band) {
#pragma unroll
        for (int i = 0; i < 4; ++i) {
            int row = i0 + band * 64 + ty * 4 + i;
            double inv_i = 1.0 / (double)nrm[row];
            int ar = band * 4 + i;
#pragma unroll
            for (int j = 0; j < 4; ++j) {
                int col = j0 + j * 16 + tx;
                G[(size_t)row * WW + col] = (float)((double)acc[ar][j] * inv_i / (double)nrm[col]);
            }
        }
    }
}

// ---------------------------------------------------------------------------
// mirror: G[j,i] = G[i,j] for strict-upper 64x64 tiles
// ---------------------------------------------------------------------------
__global__ __launch_bounds__(256) void mirror_kernel(float* __restrict__ G) {
    const int ti = blockIdx.y;
    const int tj = blockIdx.x;
    if (tj <= ti) return;
    __shared__ float tile[64][65];
    const int t = threadIdx.x;
    const int c4 = (t & 15) * 4;   // 0..60
    const int r  = t >> 4;         // 0..15
#pragma unroll
    for (int rr = r; rr < 64; rr += 16) {
        float4 v = *(const float4*)&G[(size_t)(ti * 64 + rr) * WW + tj * 64 + c4];
        tile[rr][c4 + 0] = v.x;
        tile[rr][c4 + 1] = v.y;
        tile[rr][c4 + 2] = v.z;
        tile[rr][c4 + 3] = v.w;
    }
    __syncthreads();
#pragma unroll
    for (int rr = r; rr < 64; rr += 16) {
        float4 v = make_float4(tile[c4 + 0][rr], tile[c4 + 1][rr],
                               tile[c4 + 2][rr], tile[c4 + 3][rr]);
        *(float4*)&G[(size_t)(tj * 64 + rr) * WW + ti * 64 + c4] = v;
    }
}

// ---------------------------------------------------------------------------
// R9: z in f32 VECTOR math: Z[b,w] = (sum_d (X[b,d]-bd[d]) * Ad[d,w]) / nrm[w]
// Structure = round-0's proven z_nn_f64, type-swapped. 128x64 tile, BK=16,
// 8x4 f32 microtile; A (=X-bd) staged transposed As[k][b] (scalar f32 writes,
// <=2-way banks = free), B staged float2-contiguous. f32 bias subtract
// (matches reference), f32 FMA chain, f64 epilogue divide.
// ---------------------------------------------------------------------------
__global__ __launch_bounds__(256) void z_nn_f32_kernel(const float* __restrict__ X,
                                                       const float* __restrict__ Ad,
                                                       const float* __restrict__ bd,
                                                       const float* __restrict__ nrm,
                                                       float* __restrict__ Z) {
    __shared__ __align__(16) float As[16 * 132];   // As[k][b], b=0..127 (pad 4)
    __shared__ __align__(16) float Bs[16 * 66];    // Bs[k][w], w=0..63  (pad 2)
    const int tid = threadIdx.x;
    const int tx = tid & 15;
    const int ty = tid >> 4;
    const int b0 = blockIdx.y * 128;
    const int w0 = blockIdx.x * 64;
    const int r  = tid >> 1;         // 0..127 (A staging batch-row)
    const int k8 = (tid & 1) * 8;    // 0 or 8 (A staging k offset)
    const int brow = tid >> 5;       // 0..7
    const int bpos = (tid & 31) * 2; // 0..62

    float acc[8][4];
#pragma unroll
    for (int i = 0; i < 8; ++i)
#pragma unroll
        for (int j = 0; j < 4; ++j) acc[i][j] = 0.0f;

    for (int k0 = 0; k0 < DD; k0 += 16) {
        float4 bias0 = *(const float4*)&bd[k0 + k8];
        float4 bias1 = *(const float4*)&bd[k0 + k8 + 4];
        float4 a0 = *(const float4*)&X[(size_t)(b0 + r) * DD + k0 + k8];
        float4 a1 = *(const float4*)&X[(size_t)(b0 + r) * DD + k0 + k8 + 4];
        a0.x -= bias0.x; a0.y -= bias0.y; a0.z -= bias0.z; a0.w -= bias0.w;
        a1.x -= bias1.x; a1.y -= bias1.y; a1.z -= bias1.z; a1.w -= bias1.w;
        float2 bl0 = *(const float2*)&Ad[(size_t)(k0 + brow) * WW + w0 + bpos];
        float2 bl1 = *(const float2*)&Ad[(size_t)(k0 + 8 + brow) * WW + w0 + bpos];
        __syncthreads();
        As[(k8 + 0) * 132 + r] = a0.x;
        As[(k8 + 1) * 132 + r] = a0.y;
        As[(k8 + 2) * 132 + r] = a0.z;
        As[(k8 + 3) * 132 + r] = a0.w;
        As[(k8 + 4) * 132 + r] = a1.x;
        As[(k8 + 5) * 132 + r] = a1.y;
        As[(k8 + 6) * 132 + r] = a1.z;
        As[(k8 + 7) * 132 + r] = a1.w;
        *(float2*)&Bs[brow * 66 + bpos] = bl0;
        *(float2*)&Bs[(8 + brow) * 66 + bpos] = bl1;
        __syncthreads();

#pragma unroll
        for (int kk = 0; kk < 16; ++kk) {
            const float* arw = &As[kk * 132];
            const float* bb = &Bs[kk * 66];
            float4 a0 = *(const float4*)&arw[ty * 4];
            float4 a1 = *(const float4*)&arw[64 + ty * 4];
            float av[8] = {a0.x, a0.y, a0.z, a0.w, a1.x, a1.y, a1.z, a1.w};
            float bv[4] = {bb[tx], bb[16 + tx], bb[32 + tx], bb[48 + tx]};
#pragma unroll
            for (int i = 0; i < 8; ++i)
#pragma unroll
                for (int j = 0; j < 4; ++j) acc[i][j] += av[i] * bv[j];
        }
    }

#pragma unroll
    for (int band = 0; band < 2; ++band) {
#pragma unroll
        for (int i = 0; i < 4; ++i) {
            int row = b0 + band * 64 + ty * 4 + i;
            int ar = band * 4 + i;
#pragma unroll
            for (int j = 0; j < 4; ++j) {
                int col = w0 + j * 16 + tx;
                Z[(size_t)row * WW + col] = (float)((double)acc[ar][j] / (double)nrm[col]);
            }
        }
    }
}

// ---------------------------------------------------------------------------
// Fused MP loop (R4 version, verbatim). One block per batch row; z-row in
// LDS for all 32 steps. mp is L3-BW-bound (~1.0-1.1 ms total, measured
// invariant to pairing/reg-residency) -> leave at its floor.
// ---------------------------------------------------------------------------
__global__ __launch_bounds__(256) void mp_loop_kernel(const float* __restrict__ z0,
                                                      const float* __restrict__ G,
                                                      int* __restrict__ idxL,
                                                      float* __restrict__ valL) {
    __shared__ __align__(16) float zrow[WW];   // 32 KB
    __shared__ float wv[4];
    __shared__ int   wi[4];
    const int b = blockIdx.x;
    const int t = threadIdx.x;
    float4* zs = (float4*)zrow;

    float best = -1.f;
    int bidx = 0;
    unsigned selmask = 0;   // bit j*4+e: slot (t+256*j) element e is selected

    {
        const float4* zp = (const float4*)(z0 + (size_t)b * WW);
#pragma unroll
        for (int j = 0; j < 8; ++j) {
            int slot = t + 256 * j;
            float4 v = zp[slot];
            zs[slot] = v;
            int w = slot * 4;
            float a0 = fabsf(v.x), a1 = fabsf(v.y), a2 = fabsf(v.z), a3 = fabsf(v.w);
            if (a0 > best) { best = a0; bidx = w; }
            if (a1 > best) { best = a1; bidx = w + 1; }
            if (a2 > best) { best = a2; bidx = w + 2; }
            if (a3 > best) { best = a3; bidx = w + 3; }
        }
    }

    for (int k = 0; k < KSEL; ++k) {
        float v = best;
        int i = bidx;
#pragma unroll
        for (int off = 32; off > 0; off >>= 1) {
            float ov = __shfl_xor(v, off, 64);
            int   oi = __shfl_xor(i, off, 64);
            if (ov > v || (ov == v && oi < i)) { v = ov; i = oi; }
        }
        if ((t & 63) == 0) { wv[t >> 6] = v; wi[t >> 6] = i; }
        __syncthreads();   // A: partials visible; prev phase's zrow writes visible
        float rv = wv[0];
        int   ri = wi[0];
#pragma unroll
        for (int q = 1; q < 4; ++q) {
            float qv = wv[q];
            int   qi = wi[q];
            if (qv > rv || (qv == rv && qi < ri)) { rv = qv; ri = qi; }
        }
        const int idx = ri;
        const float val = zrow[idx];   // pre-update value (LDS broadcast)
        if (t == 0) {
            idxL[(size_t)b * KSEL + k] = idx;
            valL[(size_t)b * KSEL + k] = val;
        }
        if (((idx >> 2) & 255) == t)
            selmask |= 1u << (((idx >> 10) << 2) | (idx & 3));
        if (k == KSEL - 1) break;      // final update is dead work
        __syncthreads();   // B: all threads have read val before zrow changes

        best = -1.f;
        bidx = 0;
        const float4* gr = (const float4*)(G + (size_t)idx * WW);
#pragma unroll
        for (int j = 0; j < 8; ++j) {
            int slot = t + 256 * j;
            float4 g = gr[slot];
            float4 z = zs[slot];
            unsigned m = (selmask >> (j * 4)) & 0xFu;
            float n0 = (m & 1u) ? 0.f : z.x - val * g.x;
            float n1 = (m & 2u) ? 0.f : z.y - val * g.y;
            float n2 = (m & 4u) ? 0.f : z.z - val * g.z;
            float n3 = (m & 8u) ? 0.f : z.w - val * g.w;
            zs[slot] = make_float4(n0, n1, n2, n3);
            int w = slot * 4;
            float a0 = fabsf(n0), a1 = fabsf(n1), a2 = fabsf(n2), a3 = fabsf(n3);
            if (a0 > best) { best = a0; bidx = w; }
            if (a1 > best) { best = a1; bidx = w + 1; }
            if (a2 > best) { best = a2; bidx = w + 2; }
            if (a3 > best) { best = a3; bidx = w + 3; }
        }
    }
}

// ---------------------------------------------------------------------------
// copy idx/val metadata (d_out staging -> ws), element-wise
// ---------------------------------------------------------------------------
__global__ __launch_bounds__(256) void copy_meta_kernel(const int* __restrict__ si,
                                                        const float* __restrict__ sv,
                                                        int* __restrict__ di,
                                                        float* __restrict__ dv,
                                                        int n) {
    int i = blockIdx.x * 256 + threadIdx.x;
    if (i < n) {
        di[i] = si[i];
        dv[i] = sv[i];
    }
}

// ---------------------------------------------------------------------------
// out[row, :] = bd + sum_k val[b,k] * AdnT[idx[b,k], :]
// ---------------------------------------------------------------------------
__global__ __launch_bounds__(256) void assemble_kernel(const float* __restrict__ AdnT,
                                                       const float* __restrict__ bd,
                                                       const int* __restrict__ idxL,
                                                       const float* __restrict__ valL,
                                                       float* __restrict__ out,
                                                       int rowStart) {
    __shared__ int sidx[KSEL];
    __shared__ float sval[KSEL];
    const int b = blockIdx.x;
    const int row = rowStart + b;
    const int t = threadIdx.x;
    if (t < KSEL) {
        sidx[t] = idxL[(size_t)b * KSEL + t];
        sval[t] = valL[(size_t)b * KSEL + t];
    }
    __syncthreads();
    float acc0 = bd[t];
    float acc1 = bd[t + 256];
    float acc2 = bd[t + 512];
#pragma unroll 4
    for (int k = 0; k < KSEL; ++k) {
        const float* col = AdnT + (size_t)sidx[k] * DD;
        float v = sval[k];
        acc0 += v * col[t];
        acc1 += v * col[t + 256];
        acc2 += v * col[t + 512];
    }
    out[(size_t)row * DD + t] = acc0;
    out[(size_t)row * DD + t + 256] = acc1;
    out[(size_t)row * DD + t + 512] = acc2;
}

// ---------------------------------------------------------------------------
extern "C" void kernel_launch(void* const* d_in, const int* in_sizes, int n_in,
                              void* d_out, int out_size, void* d_ws, size_t ws_size,
                              hipStream_t stream) {
    const float* x  = (const float*)d_in[0];   // [B, D]
    const float* Ad = (const float*)d_in[1];   // [D, W]
    const float* bd = (const float*)d_in[2];   // [1, D]
    float* out = (float*)d_out;                // [B, D]

    const size_t ADNT_B = (size_t)WW * DD * 4;        // 25,165,824
    const size_t NRM_B  = (size_t)WW * 4;             // 32,768
    const size_t IDX_B  = (size_t)BBATCH * KSEL * 4;  // 1,048,576
    const size_t VAL_B  = IDX_B;
    const size_t G_B    = (size_t)WW * WW * 4;        // 268,435,456 (= 256 MiB)
    const size_t ZROW_B = (size_t)WW * 4;             // 32,768
    const size_t A_MIN  = ADNT_B + NRM_B + IDX_B + VAL_B + G_B + 128 * ZROW_B;

    if (ws_size >= A_MIN) {
        // ---------------- Layout A: everything in ws ----------------
        char* p = (char*)d_ws;
        float* AdnT = (float*)p;  p += ADNT_B;
        float* nrm  = (float*)p;  p += NRM_B;
        int*   idxL = (int*)p;    p += IDX_B;
        float* valL = (float*)p;  p += VAL_B;
        float* G    = (float*)p;  p += G_B;
        float* z    = (float*)p;
        size_t z_avail = ws_size - (ADNT_B + NRM_B + IDX_B + VAL_B + G_B);
        int chunk = (int)((z_avail / ZROW_B) / 128) * 128;
        if (chunk > BBATCH) chunk = BBATCH;

        colnorm_kernel<<<WW / 256, 256, 0, stream>>>(Ad, nrm);
        gram_tn_f32_kernel<<<dim3(WW / 64, WW / 128), 256, 0, stream>>>(Ad, nrm, G);
        mirror_kernel<<<dim3(WW / 64, WW / 64), 256, 0, stream>>>(G);
        for (int r0 = 0; r0 < BBATCH; r0 += chunk) {
            int rows = (BBATCH - r0 < chunk) ? (BBATCH - r0) : chunk;
            z_nn_f32_kernel<<<dim3(WW / 64, rows / 128), 256, 0, stream>>>(
                x + (size_t)r0 * DD, Ad, bd, nrm, z);
            mp_loop_kernel<<<rows, 256, 0, stream>>>(
                z, G, idxL + (size_t)r0 * KSEL, valL + (size_t)r0 * KSEL);
        }
        transpose_scale_kernel<<<dim3(WW / 32, DD / 32), dim3(32, 8), 0, stream>>>(Ad, nrm, AdnT);
        assemble_kernel<<<BBATCH, 256, 0, stream>>>(AdnT, bd, idxL, valL, out, 0);
    } else if (ws_size >= G_B) {
        // ---------------- Layout B: ws = G only; scratch in d_out ----------------
        // d_out carve (25,165,824 B total):
        //   [0 .. 20,971,520)          z chunks (512 rows x 32 KB used)
        //   [20,971,520 .. 21,004,288) nrm (32 KB)
        //   [23,068,672 .. 24,117,248) idxL [B,32]
        //   [24,117,248 .. 25,165,824) valL [B,32]
        float* G    = (float*)d_ws;
        char*  ob   = (char*)d_out;
        float* z    = (float*)ob;
        float* nrm  = (float*)(ob + 20971520);
        int*   idxL = (int*)(ob + 23068672);
        float* valL = (float*)(ob + 24117248);
        // after MP loops, G is dead -> reuse ws:
        float* AdnT = (float*)d_ws;
        int*   idx2 = (int*)((char*)d_ws + ADNT_B);
        float* val2 = (float*)((char*)d_ws + ADNT_B + IDX_B);
        const int chunk = 512;   // 4 x 128 rows -> 512 mp blocks = exactly 2/CU

        colnorm_kernel<<<WW / 256, 256, 0, stream>>>(Ad, nrm);
        gram_tn_f32_kernel<<<dim3(WW / 64, WW / 128), 256, 0, stream>>>(Ad, nrm, G);
        mirror_kernel<<<dim3(WW / 64, WW / 64), 256, 0, stream>>>(G);
        for (int r0 = 0; r0 < BBATCH; r0 += chunk) {
            int rows = (BBATCH - r0 < chunk) ? (BBATCH - r0) : chunk;
            z_nn_f32_kernel<<<dim3(WW / 64, rows / 128), 256, 0, stream>>>(
                x + (size_t)r0 * DD, Ad, bd, nrm, z);
            mp_loop_kernel<<<rows, 256, 0, stream>>>(
                z, G, idxL + (size_t)r0 * KSEL, valL + (size_t)r0 * KSEL);
        }
        {
            int n = BBATCH * KSEL;
            copy_meta_kernel<<<(n + 255) / 256, 256, 0, stream>>>(idxL, valL, idx2, val2, n);
        }
        transpose_scale_kernel<<<dim3(WW / 32, DD / 32), dim3(32, 8), 0, stream>>>(Ad, nrm, AdnT);
        assemble_kernel<<<BBATCH, 256, 0, stream>>>(AdnT, bd, idx2, val2, out, 0);
    }
    // else: ws too small for any fp32-G plan -> leave output zeroed (clean fail)
}

// Round 10
// 3986.987 us; speedup vs baseline: 1.3385x; 1.0011x over previous
//
#include <hip/hip_runtime.h>
#include <cstddef>

// Problem constants (fixed by the reference)
static const int WW = 8192;     // width (atoms)
static const int DD = 768;      // input dim
static const int BBATCH = 8192; // batch
static const int KSEL = 32;     // MP steps

// ---------------------------------------------------------------------------
// column norms of Ad [D, W] -> nrm[W] = max(||Ad[:,w]||, 1e-8), fp64 accumulate
// ---------------------------------------------------------------------------
__global__ __launch_bounds__(256) void colnorm_kernel(const float* __restrict__ Ad,
                                                      float* __restrict__ nrm) {
    int w = blockIdx.x * 256 + threadIdx.x;
    double s = 0.0;
    for (int d = 0; d < DD; ++d) {
        double v = (double)Ad[(size_t)d * WW + w];
        s += v * v;
    }
    nrm[w] = fmaxf((float)sqrt(s), 1e-8f);
}

// ---------------------------------------------------------------------------
// AdnT[w, d] = Ad[d, w] / nrm[w]   (LDS tiled transpose, 32x32)
// ---------------------------------------------------------------------------
__global__ __launch_bounds__(256) void transpose_scale_kernel(const float* __restrict__ Ad,
                                                              const float* __restrict__ nrm,
                                                              float* __restrict__ AdnT) {
    __shared__ float tile[32][33];
    int wb = blockIdx.x * 32;
    int db = blockIdx.y * 32;
    int tx = threadIdx.x;   // 0..31
    int ty = threadIdx.y;   // 0..7
    for (int i = ty; i < 32; i += 8)
        tile[i][tx] = Ad[(size_t)(db + i) * WW + (wb + tx)];
    __syncthreads();
    for (int i = ty; i < 32; i += 8)
        AdnT[(size_t)(wb + i) * DD + (db + tx)] = tile[tx][i] / nrm[wb + i];
}

// ---------------------------------------------------------------------------
// R10: Gram f32, 128x128 tile (was 128x64). R9 measured: FMA-issue = 333 us
// of 880; rest is staging/barrier overhead per FLOP, which tile size
// controls. 8x8 microtile -> 1024 FMA/thread per K-step at the same 2
// barriers; staging bytes/FLOP halve. LDS 16.9 KB, ~110 VGPR.
// Per-element k-order unchanged -> G bitwise-identical to R9.
// Upper 128-blocks only (by <= bx); mirror fills strict-lower 64-tiles
// (every strict-upper 64-tile is inside a computed 128-block).
// ---------------------------------------------------------------------------
__global__ __launch_bounds__(256) void gram_tn_f32_kernel(const float* __restrict__ Ad,
                                                          const float* __restrict__ nrm,
                                                          float* __restrict__ G) {
    const int bx = blockIdx.x, by = blockIdx.y;
    if (by > bx) return;   // strictly-lower 128-block -> mirror fills
    __shared__ __align__(16) float As[16 * 132];   // As[k][i], i=0..127 (pad 4)
    __shared__ __align__(16) float Bs[16 * 132];   // Bs[k][j], j=0..127 (pad 4)
    const int tid = threadIdx.x;
    const int tx = tid & 15;         // 0..15 (col group)
    const int ty = tid >> 4;         // 0..15 (row group)
    const int i0 = by * 128;
    const int j0 = bx * 128;
    const int ar0 = tid >> 6;        // 0..3
    const int ap0 = (tid & 63) * 2;  // 0..126

    float acc[8][8];
#pragma unroll
    for (int i = 0; i < 8; ++i)
#pragma unroll
        for (int j = 0; j < 8; ++j) acc[i][j] = 0.0f;

    for (int k0 = 0; k0 < DD; k0 += 16) {
        float2 aL[4], bL[4];
#pragma unroll
        for (int q = 0; q < 4; ++q) {
            aL[q] = *(const float2*)&Ad[(size_t)(k0 + 4 * q + ar0) * WW + i0 + ap0];
            bL[q] = *(const float2*)&Ad[(size_t)(k0 + 4 * q + ar0) * WW + j0 + ap0];
        }
        __syncthreads();   // previous iteration's LDS reads done
#pragma unroll
        for (int q = 0; q < 4; ++q) {
            *(float2*)&As[(4 * q + ar0) * 132 + ap0] = aL[q];
            *(float2*)&Bs[(4 * q + ar0) * 132 + ap0] = bL[q];
        }
        __syncthreads();

#pragma unroll
        for (int kk = 0; kk < 16; ++kk) {
            const float* arw = &As[kk * 132];
            const float* bb = &Bs[kk * 132];
            float4 a0 = *(const float4*)&arw[ty * 4];        // broadcast reads
            float4 a1 = *(const float4*)&arw[64 + ty * 4];
            float av[8] = {a0.x, a0.y, a0.z, a0.w, a1.x, a1.y, a1.z, a1.w};
            float bv[8] = {bb[tx], bb[16 + tx], bb[32 + tx], bb[48 + tx],
                           bb[64 + tx], bb[80 + tx], bb[96 + tx], bb[112 + tx]};
#pragma unroll
            for (int i = 0; i < 8; ++i)
#pragma unroll
                for (int j = 0; j < 8; ++j) acc[i][j] += av[i] * bv[j];
        }
    }

#pragma unroll
    for (int band = 0; band < 2; ++band) {
#pragma unroll
        for (int i = 0; i < 4; ++i) {
            int row = i0 + band * 64 + ty * 4 + i;
            double inv_i = 1.0 / (double)nrm[row];
            int ar = band * 4 + i;
#pragma unroll
            for (int j = 0; j < 8; ++j) {
                int col = j0 + j * 16 + tx;
                G[(size_t)row * WW + col] = (float)((double)acc[ar][j] * inv_i / (double)nrm[col]);
            }
        }
    }
}

// ---------------------------------------------------------------------------
// mirror: G[j,i] = G[i,j] for strict-upper 64x64 tiles
// ---------------------------------------------------------------------------
__global__ __launch_bounds__(256) void mirror_kernel(float* __restrict__ G) {
    const int ti = blockIdx.y;
    const int tj = blockIdx.x;
    if (tj <= ti) return;
    __shared__ float tile[64][65];
    const int t = threadIdx.x;
    const int c4 = (t & 15) * 4;   // 0..60
    const int r  = t >> 4;         // 0..15
#pragma unroll
    for (int rr = r; rr < 64; rr += 16) {
        float4 v = *(const float4*)&G[(size_t)(ti * 64 + rr) * WW + tj * 64 + c4];
        tile[rr][c4 + 0] = v.x;
        tile[rr][c4 + 1] = v.y;
        tile[rr][c4 + 2] = v.z;
        tile[rr][c4 + 3] = v.w;
    }
    __syncthreads();
#pragma unroll
    for (int rr = r; rr < 64; rr += 16) {
        float4 v = make_float4(tile[c4 + 0][rr], tile[c4 + 1][rr],
                               tile[c4 + 2][rr], tile[c4 + 3][rr]);
        *(float4*)&G[(size_t)(tj * 64 + rr) * WW + ti * 64 + c4] = v;
    }
}

// ---------------------------------------------------------------------------
// R10: z f32, same 128x64 output mapping/grid as R9 (residency: 512 blocks
// per 512-row chunk), but BK 16 -> 32: barrier count halves, staging total
// unchanged. Per-element FMA order unchanged (k ascending) -> Z bitwise-
// identical to R9. LDS 25.3 KB.
// ---------------------------------------------------------------------------
__global__ __launch_bounds__(256) void z_nn_f32_kernel(const float* __restrict__ X,
                                                       const float* __restrict__ Ad,
                                                       const float* __restrict__ bd,
                                                       const float* __restrict__ nrm,
                                                       float* __restrict__ Z) {
    __shared__ __align__(16) float As[32 * 132];   // As[k][b], b=0..127 (pad 4)
    __shared__ __align__(16) float Bs[32 * 66];    // Bs[k][w], w=0..63  (pad 2)
    const int tid = threadIdx.x;
    const int tx = tid & 15;
    const int ty = tid >> 4;
    const int b0 = blockIdx.y * 128;
    const int w0 = blockIdx.x * 64;
    const int r   = tid >> 1;         // 0..127 (A staging batch-row)
    const int k16 = (tid & 1) * 16;   // 0 or 16 (A staging k offset)
    const int brow = tid >> 5;        // 0..7
    const int bpos = (tid & 31) * 2;  // 0..62

    float acc[8][4];
#pragma unroll
    for (int i = 0; i < 8; ++i)
#pragma unroll
        for (int j = 0; j < 4; ++j) acc[i][j] = 0.0f;

    for (int k0 = 0; k0 < DD; k0 += 32) {
        float4 aV[4];
#pragma unroll
        for (int c = 0; c < 4; ++c) {
            float4 bias = *(const float4*)&bd[k0 + k16 + 4 * c];
            float4 a = *(const float4*)&X[(size_t)(b0 + r) * DD + k0 + k16 + 4 * c];
            a.x -= bias.x; a.y -= bias.y; a.z -= bias.z; a.w -= bias.w;
            aV[c] = a;
        }
        float2 bV[4];
#pragma unroll
        for (int s = 0; s < 4; ++s)
            bV[s] = *(const float2*)&Ad[(size_t)(k0 + 8 * s + brow) * WW + w0 + bpos];
        __syncthreads();   // previous iteration's LDS reads done
#pragma unroll
        for (int c = 0; c < 4; ++c) {
            As[(k16 + 4 * c + 0) * 132 + r] = aV[c].x;
            As[(k16 + 4 * c + 1) * 132 + r] = aV[c].y;
            As[(k16 + 4 * c + 2) * 132 + r] = aV[c].z;
            As[(k16 + 4 * c + 3) * 132 + r] = aV[c].w;
        }
#pragma unroll
        for (int s = 0; s < 4; ++s)
            *(float2*)&Bs[(8 * s + brow) * 66 + bpos] = bV[s];
        __syncthreads();

#pragma unroll
        for (int kk = 0; kk < 32; ++kk) {
            const float* arw = &As[kk * 132];
            const float* bb = &Bs[kk * 66];
            float4 a0 = *(const float4*)&arw[ty * 4];
            float4 a1 = *(const float4*)&arw[64 + ty * 4];
            float av[8] = {a0.x, a0.y, a0.z, a0.w, a1.x, a1.y, a1.z, a1.w};
            float bv[4] = {bb[tx], bb[16 + tx], bb[32 + tx], bb[48 + tx]};
#pragma unroll
            for (int i = 0; i < 8; ++i)
#pragma unroll
                for (int j = 0; j < 4; ++j) acc[i][j] += av[i] * bv[j];
        }
    }

#pragma unroll
    for (int band = 0; band < 2; ++band) {
#pragma unroll
        for (int i = 0; i < 4; ++i) {
            int row = b0 + band * 64 + ty * 4 + i;
            int ar = band * 4 + i;
#pragma unroll
            for (int j = 0; j < 4; ++j) {
                int col = w0 + j * 16 + tx;
                Z[(size_t)row * WW + col] = (float)((double)acc[ar][j] / (double)nrm[col]);
            }
        }
    }
}

// ---------------------------------------------------------------------------
// Fused MP loop (R4/R9 version, verbatim). One block per batch row; z-row in
// LDS for all 32 steps. mp is L3-BW-bound (~1.0-1.1 ms total, measured
// invariant to pairing/reg-residency) -> at its floor.
// ---------------------------------------------------------------------------
__global__ __launch_bounds__(256) void mp_loop_kernel(const float* __restrict__ z0,
                                                      const float* __restrict__ G,
                                                      int* __restrict__ idxL,
                                                      float* __restrict__ valL) {
    __shared__ __align__(16) float zrow[WW];   // 32 KB
    __shared__ float wv[4];
    __shared__ int   wi[4];
    const int b = blockIdx.x;
    const int t = threadIdx.x;
    float4* zs = (float4*)zrow;

    float best = -1.f;
    int bidx = 0;
    unsigned selmask = 0;   // bit j*4+e: slot (t+256*j) element e is selected

    {
        const float4* zp = (const float4*)(z0 + (size_t)b * WW);
#pragma unroll
        for (int j = 0; j < 8; ++j) {
            int slot = t + 256 * j;
            float4 v = zp[slot];
            zs[slot] = v;
            int w = slot * 4;
            float a0 = fabsf(v.x), a1 = fabsf(v.y), a2 = fabsf(v.z), a3 = fabsf(v.w);
            if (a0 > best) { best = a0; bidx = w; }
            if (a1 > best) { best = a1; bidx = w + 1; }
            if (a2 > best) { best = a2; bidx = w + 2; }
            if (a3 > best) { best = a3; bidx = w + 3; }
        }
    }

    for (int k = 0; k < KSEL; ++k) {
        float v = best;
        int i = bidx;
#pragma unroll
        for (int off = 32; off > 0; off >>= 1) {
            float ov = __shfl_xor(v, off, 64);
            int   oi = __shfl_xor(i, off, 64);
            if (ov > v || (ov == v && oi < i)) { v = ov; i = oi; }
        }
        if ((t & 63) == 0) { wv[t >> 6] = v; wi[t >> 6] = i; }
        __syncthreads();   // A: partials visible; prev phase's zrow writes visible
        float rv = wv[0];
        int   ri = wi[0];
#pragma unroll
        for (int q = 1; q < 4; ++q) {
            float qv = wv[q];
            int   qi = wi[q];
            if (qv > rv || (qv == rv && qi < ri)) { rv = qv; ri = qi; }
        }
        const int idx = ri;
        const float val = zrow[idx];   // pre-update value (LDS broadcast)
        if (t == 0) {
            idxL[(size_t)b * KSEL + k] = idx;
            valL[(size_t)b * KSEL + k] = val;
        }
        if (((idx >> 2) & 255) == t)
            selmask |= 1u << (((idx >> 10) << 2) | (idx & 3));
        if (k == KSEL - 1) break;      // final update is dead work
        __syncthreads();   // B: all threads have read val before zrow changes

        best = -1.f;
        bidx = 0;
        const float4* gr = (const float4*)(G + (size_t)idx * WW);
#pragma unroll
        for (int j = 0; j < 8; ++j) {
            int slot = t + 256 * j;
            float4 g = gr[slot];
            float4 z = zs[slot];
            unsigned m = (selmask >> (j * 4)) & 0xFu;
            float n0 = (m & 1u) ? 0.f : z.x - val * g.x;
            float n1 = (m & 2u) ? 0.f : z.y - val * g.y;
            float n2 = (m & 4u) ? 0.f : z.z - val * g.z;
            float n3 = (m & 8u) ? 0.f : z.w - val * g.w;
            zs[slot] = make_float4(n0, n1, n2, n3);
            int w = slot * 4;
            float a0 = fabsf(n0), a1 = fabsf(n1), a2 = fabsf(n2), a3 = fabsf(n3);
            if (a0 > best) { best = a0; bidx = w; }
            if (a1 > best) { best = a1; bidx = w + 1; }
            if (a2 > best) { best = a2; bidx = w + 2; }
            if (a3 > best) { best = a3; bidx = w + 3; }
        }
    }
}

// ---------------------------------------------------------------------------
// copy idx/val metadata (d_out staging -> ws), element-wise
// ---------------------------------------------------------------------------
__global__ __launch_bounds__(256) void copy_meta_kernel(const int* __restrict__ si,
                                                        const float* __restrict__ sv,
                                                        int* __restrict__ di,
                                                        float* __restrict__ dv,
                                                        int n) {
    int i = blockIdx.x * 256 + threadIdx.x;
    if (i < n) {
        di[i] = si[i];
        dv[i] = sv[i];
    }
}

// ---------------------------------------------------------------------------
// out[row, :] = bd + sum_k val[b,k] * AdnT[idx[b,k], :]
// ---------------------------------------------------------------------------
__global__ __launch_bounds__(256) void assemble_kernel(const float* __restrict__ AdnT,
                                                       const float* __restrict__ bd,
                                                       const int* __restrict__ idxL,
                                                       const float* __restrict__ valL,
                                                       float* __restrict__ out,
                                                       int rowStart) {
    __shared__ int sidx[KSEL];
    __shared__ float sval[KSEL];
    const int b = blockIdx.x;
    const int row = rowStart + b;
    const int t = threadIdx.x;
    if (t < KSEL) {
        sidx[t] = idxL[(size_t)b * KSEL + t];
        sval[t] = valL[(size_t)b * KSEL + t];
    }
    __syncthreads();
    float acc0 = bd[t];
    float acc1 = bd[t + 256];
    float acc2 = bd[t + 512];
#pragma unroll 4
    for (int k = 0; k < KSEL; ++k) {
        const float* col = AdnT + (size_t)sidx[k] * DD;
        float v = sval[k];
        acc0 += v * col[t];
        acc1 += v * col[t + 256];
        acc2 += v * col[t + 512];
    }
    out[(size_t)row * DD + t] = acc0;
    out[(size_t)row * DD + t + 256] = acc1;
    out[(size_t)row * DD + t + 512] = acc2;
}

// ---------------------------------------------------------------------------
extern "C" void kernel_launch(void* const* d_in, const int* in_sizes, int n_in,
                              void* d_out, int out_size, void* d_ws, size_t ws_size,
                              hipStream_t stream) {
    const float* x  = (const float*)d_in[0];   // [B, D]
    const float* Ad = (const float*)d_in[1];   // [D, W]
    const float* bd = (const float*)d_in[2];   // [1, D]
    float* out = (float*)d_out;                // [B, D]

    const size_t ADNT_B = (size_t)WW * DD * 4;        // 25,165,824
    const size_t NRM_B  = (size_t)WW * 4;             // 32,768
    const size_t IDX_B  = (size_t)BBATCH * KSEL * 4;  // 1,048,576
    const size_t VAL_B  = IDX_B;
    const size_t G_B    = (size_t)WW * WW * 4;        // 268,435,456 (= 256 MiB)
    const size_t ZROW_B = (size_t)WW * 4;             // 32,768
    const size_t A_MIN  = ADNT_B + NRM_B + IDX_B + VAL_B + G_B + 128 * ZROW_B;

    if (ws_size >= A_MIN) {
        // ---------------- Layout A: everything in ws ----------------
        char* p = (char*)d_ws;
        float* AdnT = (float*)p;  p += ADNT_B;
        float* nrm  = (float*)p;  p += NRM_B;
        int*   idxL = (int*)p;    p += IDX_B;
        float* valL = (float*)p;  p += VAL_B;
        float* G    = (float*)p;  p += G_B;
        float* z    = (float*)p;
        size_t z_avail = ws_size - (ADNT_B + NRM_B + IDX_B + VAL_B + G_B);
        int chunk = (int)((z_avail / ZROW_B) / 128) * 128;
        if (chunk > BBATCH) chunk = BBATCH;

        colnorm_kernel<<<WW / 256, 256, 0, stream>>>(Ad, nrm);
        gram_tn_f32_kernel<<<dim3(WW / 128, WW / 128), 256, 0, stream>>>(Ad, nrm, G);
        mirror_kernel<<<dim3(WW / 64, WW / 64), 256, 0, stream>>>(G);
        for (int r0 = 0; r0 < BBATCH; r0 += chunk) {
            int rows = (BBATCH - r0 < chunk) ? (BBATCH - r0) : chunk;
            z_nn_f32_kernel<<<dim3(WW / 64, rows / 128), 256, 0, stream>>>(
                x + (size_t)r0 * DD, Ad, bd, nrm, z);
            mp_loop_kernel<<<rows, 256, 0, stream>>>(
                z, G, idxL + (size_t)r0 * KSEL, valL + (size_t)r0 * KSEL);
        }
        transpose_scale_kernel<<<dim3(WW / 32, DD / 32), dim3(32, 8), 0, stream>>>(Ad, nrm, AdnT);
        assemble_kernel<<<BBATCH, 256, 0, stream>>>(AdnT, bd, idxL, valL, out, 0);
    } else if (ws_size >= G_B) {
        // ---------------- Layout B: ws = G only; scratch in d_out ----------------
        // d_out carve (25,165,824 B total):
        //   [0 .. 20,971,520)          z chunks (512 rows x 32 KB used)
        //   [20,971,520 .. 21,004,288) nrm (32 KB)
        //   [23,068,672 .. 24,117,248) idxL [B,32]
        //   [24,117,248 .. 25,165,824) valL [B,32]
        float* G    = (float*)d_ws;
        char*  ob   = (char*)d_out;
        float* z    = (float*)ob;
        float* nrm  = (float*)(ob + 20971520);
        int*   idxL = (int*)(ob + 23068672);
        float* valL = (float*)(ob + 24117248);
        // after MP loops, G is dead -> reuse ws:
        float* AdnT = (float*)d_ws;
        int*   idx2 = (int*)((char*)d_ws + ADNT_B);
        float* val2 = (float*)((char*)d_ws + ADNT_B + IDX_B);
        const int chunk = 512;   // 4 x 128 rows -> 512 mp blocks = exactly 2/CU

        colnorm_kernel<<<WW / 256, 256, 0, stream>>>(Ad, nrm);
        gram_tn_f32_kernel<<<dim3(WW / 128, WW / 128), 256, 0, stream>>>(Ad, nrm, G);
        mirror_kernel<<<dim3(WW / 64, WW / 64), 256, 0, stream>>>(G);
        for (int r0 = 0; r0 < BBATCH; r0 += chunk) {
            int rows = (BBATCH - r0 < chunk) ? (BBATCH - r0) : chunk;
            z_nn_f32_kernel<<<dim3(WW / 64, rows / 128), 256, 0, stream>>>(
                x + (size_t)r0 * DD, Ad, bd, nrm, z);
            mp_loop_kernel<<<rows, 256, 0, stream>>>(
                z, G, idxL + (size_t)r0 * KSEL, valL + (size_t)r0 * KSEL);
        }
        {
            int n = BBATCH * KSEL;
            copy_meta_kernel<<<(n + 255) / 256, 256, 0, stream>>>(idxL, valL, idx2, val2, n);
        }
        transpose_scale_kernel<<<dim3(WW / 32, DD / 32), dim3(32, 8), 0, stream>>>(Ad, nrm, AdnT);
        assemble_kernel<<<BBATCH, 256, 0, stream>>>(AdnT, bd, idx2, val2, out, 0);
    }
    // else: ws too small for any fp32-G plan -> leave output zeroed (clean fail)
}